// Round 12
// baseline (1949.251 us; speedup 1.0000x reference)
//
#include <hip/hip_runtime.h>

typedef unsigned short u16;
typedef short bf16x8 __attribute__((ext_vector_type(8)));
typedef float f32x4 __attribute__((ext_vector_type(4)));
typedef u16 u16x4 __attribute__((ext_vector_type(4)));

#define TT     1024
#define EE     768
#define NHH    12
#define ND     2048
#define VOC    32000
#define HNN    24576
#define NLAYER 6
#define LN_EPS 1e-5f
#define SPLITK 16

// ---------- bf16 helpers ----------
__device__ __forceinline__ float b2f(u16 u){
  unsigned int x = ((unsigned int)u) << 16; float f; __builtin_memcpy(&f, &x, 4); return f;
}
__device__ __forceinline__ u16 f2b(float f){
  unsigned int x; __builtin_memcpy(&x, &f, 4);
  x = x + 0x7fffu + ((x >> 16) & 1u);
  return (u16)(x >> 16);
}

__device__ __forceinline__ void gload16(const void* g, void* lds){
  __builtin_amdgcn_global_load_lds(
      (const __attribute__((address_space(1))) unsigned int*)g,
      (__attribute__((address_space(3))) unsigned int*)(unsigned int)(unsigned long long)lds,
      16, 0, 0);
}

__device__ __forceinline__ bf16x8 ldsr(unsigned addr){
  bf16x8 r;
  asm volatile("ds_read_b128 %0, %1" : "=v"(r) : "v"(addr));
  return r;
}

// ---------- block reductions (256 threads = 4 waves) ----------
__device__ __forceinline__ void blk_sum2(float& a, float& b){
  #pragma unroll
  for (int o = 32; o > 0; o >>= 1){ a += __shfl_down(a, o); b += __shfl_down(b, o); }
  __shared__ float sa[4], sb[4];
  int lane = threadIdx.x & 63, wid = threadIdx.x >> 6;
  __syncthreads();
  if (lane == 0){ sa[wid] = a; sb[wid] = b; }
  __syncthreads();
  a = (sa[0] + sa[1]) + (sa[2] + sa[3]);
  b = (sb[0] + sb[1]) + (sb[2] + sb[3]);
}
__device__ __forceinline__ float blk_max(float v){
  #pragma unroll
  for (int o = 32; o > 0; o >>= 1) v = fmaxf(v, __shfl_down(v, o));
  __shared__ float sm[4];
  int lane = threadIdx.x & 63, wid = threadIdx.x >> 6;
  __syncthreads();
  if (lane == 0) sm[wid] = v;
  __syncthreads();
  return fmaxf(fmaxf(sm[0], sm[1]), fmaxf(sm[2], sm[3]));
}
__device__ __forceinline__ float blk_sum(float v){
  #pragma unroll
  for (int o = 32; o > 0; o >>= 1) v += __shfl_down(v, o);
  __shared__ float ss[4];
  int lane = threadIdx.x & 63, wid = threadIdx.x >> 6;
  __syncthreads();
  if (lane == 0) ss[wid] = v;
  __syncthreads();
  return (ss[0] + ss[1]) + (ss[2] + ss[3]);
}

// ---------- merged weight preprocessing (3 transposes + lm_head cast) ----------
__global__ void prep(const float* __restrict__ enc, const float* __restrict__ encv,
                     const float* __restrict__ dec, const float* __restrict__ lmh,
                     u16* __restrict__ encT, u16* __restrict__ encvT,
                     u16* __restrict__ decT, u16* __restrict__ lmhB){
  __shared__ float tile[32][33];
  int b = blockIdx.x;
  int lx = threadIdx.x & 31, ly = threadIdx.x >> 5;
  if (b < 36864){
    const float* in; u16* out;
    if (b < 18432){ in = enc; out = encT; } else { in = encv; out = encvT; b -= 18432; }
    int z = b / 1536, rem = b - z * 1536;
    int c0 = (rem & 63) * 32, r0 = (rem >> 6) * 32;      // c over ND, r over EE
    in  += (long)z * EE * ND;
    out += (long)z * ND * EE;
    #pragma unroll
    for (int i = 0; i < 32; i += 8)
      tile[ly + i][lx] = in[(long)(r0 + ly + i) * ND + c0 + lx];
    __syncthreads();
    #pragma unroll
    for (int i = 0; i < 32; i += 8)
      out[(long)(c0 + ly + i) * EE + r0 + lx] = f2b(tile[lx][ly + i]);
  } else if (b < 55296){
    b -= 36864;
    int c0 = (b % 24) * 32, r0 = (b / 24) * 32;          // c over EE, r over HNN
    #pragma unroll
    for (int i = 0; i < 32; i += 8)
      tile[ly + i][lx] = dec[(long)(r0 + ly + i) * EE + c0 + lx];
    __syncthreads();
    #pragma unroll
    for (int i = 0; i < 32; i += 8)
      decT[(long)(c0 + ly + i) * HNN + r0 + lx] = f2b(tile[lx][ly + i]);
  } else {
    b -= 55296;
    long i = ((long)b * 256 + threadIdx.x) * 4;
    float4 v = *(const float4*)(lmh + i);
    u16x4 o; o.x = f2b(v.x); o.y = f2b(v.y); o.z = f2b(v.z); o.w = f2b(v.w);
    *(u16x4*)(lmhB + i) = o;
  }
}

// ---------- coalesced bf16 transpose: xT[e][t] = xb[t][e] ----------
__global__ void xpose(const u16* __restrict__ in, u16* __restrict__ out){
  __shared__ u16 t[64][65];
  int e0 = blockIdx.x * 64, t0 = blockIdx.y * 64;
  int lx = threadIdx.x & 63, ly = threadIdx.x >> 6;   // 64 x 4
  #pragma unroll
  for (int i = 0; i < 64; i += 4)
    t[ly + i][lx] = in[(long)(t0 + ly + i) * EE + e0 + lx];
  __syncthreads();
  #pragma unroll
  for (int i = 0; i < 64; i += 4)
    out[(long)(e0 + ly + i) * TT + t0 + lx] = t[lx][ly + i];
}

// ---------- embed gather + LN (vectorized: 192 threads x float4) ----------
__global__ void embed_ln(const int* __restrict__ idx, const float* __restrict__ emb,
                         const float* __restrict__ w, const float* __restrict__ b,
                         float* __restrict__ xf, u16* __restrict__ xb){
  int t = blockIdx.x, tid = threadIdx.x;
  const float* src = emb + (long)idx[t] * EE;
  float v[4] = {0.f, 0.f, 0.f, 0.f};
  if (tid < 192){
    float4 r = *(const float4*)&src[tid * 4];
    v[0] = r.x; v[1] = r.y; v[2] = r.z; v[3] = r.w;
  }
  float s = (v[0] + v[1]) + (v[2] + v[3]);
  float s2 = (v[0]*v[0] + v[1]*v[1]) + (v[2]*v[2] + v[3]*v[3]);
  blk_sum2(s, s2);
  float m  = s * (1.0f / EE);
  float var = s2 * (1.0f / EE) - m * m;
  float rs = rsqrtf(var + LN_EPS);
  if (tid < 192){
    int e0 = tid * 4;
    float4 o; u16x4 ob;
    float* op = &o.x;
    #pragma unroll
    for (int j = 0; j < 4; j++){
      float ov = (v[j] - m) * rs * w[e0 + j] + b[e0 + j];
      op[j] = ov; ob[j] = f2b(ov);
    }
    *(float4*)&xf[(long)t * EE + e0] = o;
    *(u16x4*)&xb[(long)t * EE + e0] = ob;
  }
}

// ---------- row LN, bf16 in -> bf16 out (vectorized) ----------
__global__ void ln_rows(const u16* __restrict__ in, u16* __restrict__ out,
                        const float* __restrict__ w, const float* __restrict__ b){
  long row = blockIdx.x; int tid = threadIdx.x;
  const u16* src = in + row * EE;
  float v[4] = {0.f, 0.f, 0.f, 0.f};
  if (tid < 192){
    u16x4 r = *(const u16x4*)&src[tid * 4];
    #pragma unroll
    for (int j = 0; j < 4; j++) v[j] = b2f(r[j]);
  }
  float s = (v[0] + v[1]) + (v[2] + v[3]);
  float s2 = (v[0]*v[0] + v[1]*v[1]) + (v[2]*v[2] + v[3]*v[3]);
  blk_sum2(s, s2);
  float m = s * (1.0f / EE);
  float var = s2 * (1.0f / EE) - m * m;
  float rs = rsqrtf(var + LN_EPS);
  if (tid < 192){
    int e0 = tid * 4;
    u16x4 ob;
    #pragma unroll
    for (int j = 0; j < 4; j++) ob[j] = f2b((v[j] - m) * rs * w[e0 + j] + b[e0 + j]);
    *(u16x4*)&out[row * EE + e0] = ob;
  }
}

// ---------- softmax, causal prefix only, bf16 in/out, vectorized ----------
__global__ void softmax_rows(const u16* __restrict__ scores, u16* __restrict__ attn){
  int q = blockIdx.x, h = blockIdx.y, tid = threadIdx.x;
  const u16* srow = scores + ((long)h * TT + q) * TT;
  u16* arow = attn + ((long)h * TT + q) * TT;
  const int len = q + 1;
  const int pad = (q + 128) & ~127;
  u16x4 raw = *(const u16x4*)&srow[tid * 4];           // row is TT wide: always in-bounds
  float v[4];
  float mx = -1e30f;
  #pragma unroll
  for (int j = 0; j < 4; j++){
    int i = tid * 4 + j;
    v[j] = (i < len) ? b2f(raw[j]) : -1e30f;           // mask garbage before use
    mx = fmaxf(mx, v[j]);
  }
  mx = blk_max(mx);
  float s = 0.f;
  #pragma unroll
  for (int j = 0; j < 4; j++){
    int i = tid * 4 + j;
    float e = (i < len) ? __expf(v[j] - mx) : 0.f;
    v[j] = e; s += e;
  }
  float inv = 1.0f / blk_sum(s);
  int i0 = tid * 4;
  if (i0 < pad){                                        // pad mult of 128 -> full vec in range
    u16x4 o;
    #pragma unroll
    for (int j = 0; j < 4; j++) o[j] = (i0 + j < len) ? f2b(v[j] * inv) : (u16)0;
    *(u16x4*)&arow[i0] = o;
  }
}

// ---------- residual: x = ln(x + ln(sum_p part_p)), part bf16, vectorized ----------
template<int P>
__global__ void residual_ln(const u16* __restrict__ part, const float* __restrict__ xin,
                            float* __restrict__ xf, u16* __restrict__ xb,
                            const float* __restrict__ w, const float* __restrict__ b){
  int t = blockIdx.x, tid = threadIdx.x;
  float g[4] = {0.f, 0.f, 0.f, 0.f};
  if (tid < 192){
    int e0 = tid * 4;
    #pragma unroll
    for (int pp = 0; pp < P; pp++){
      u16x4 r = *(const u16x4*)&part[((long)pp * TT + t) * EE + e0];
      #pragma unroll
      for (int j = 0; j < 4; j++) g[j] += b2f(r[j]);
    }
  }
  float s = (g[0] + g[1]) + (g[2] + g[3]);
  float s2 = (g[0]*g[0] + g[1]*g[1]) + (g[2]*g[2] + g[3]*g[3]);
  blk_sum2(s, s2);
  float m = s * (1.0f / EE), var = s2 * (1.0f / EE) - m * m;
  float rs = rsqrtf(var + LN_EPS);
  float hh[4] = {0.f, 0.f, 0.f, 0.f};
  if (tid < 192){
    int e0 = tid * 4;
    float4 xi = *(const float4*)&xin[(long)t * EE + e0];
    const float* xp = &xi.x;
    #pragma unroll
    for (int j = 0; j < 4; j++)
      hh[j] = xp[j] + ((g[j] - m) * rs * w[e0 + j] + b[e0 + j]);
  }
  s = (hh[0] + hh[1]) + (hh[2] + hh[3]);
  s2 = (hh[0]*hh[0] + hh[1]*hh[1]) + (hh[2]*hh[2] + hh[3]*hh[3]);
  blk_sum2(s, s2);
  m = s * (1.0f / EE); var = s2 * (1.0f / EE) - m * m; rs = rsqrtf(var + LN_EPS);
  if (tid < 192){
    int e0 = tid * 4;
    float4 o; u16x4 ob;
    float* op = &o.x;
    #pragma unroll
    for (int j = 0; j < 4; j++){
      float ov = (hh[j] - m) * rs * w[e0 + j] + b[e0 + j];
      op[j] = ov; ob[j] = f2b(ov);
    }
    *(float4*)&xf[(long)t * EE + e0] = o;
    *(u16x4*)&xb[(long)t * EE + e0] = ob;
  }
}

// ==========================================================================
// g8: 256x256 8-phase NT GEMM. Sync structure unchanged (r9-r11, verified).
// NEW: K-offset stagger s0 per block; physical tile p(t) = (s0+t) mod NT.
// Wrapped tail prefetches land only in buffer regions whose readers passed
// their closing barrier (same proof as before); scratch region dropped.
// EPI: 0=f32 | 1=relu->bf16 | 2=*scale->bf16 (causal skip) | 3=relu*Mul->bf16
// ==========================================================================
template<int EPI>
__global__ __launch_bounds__(512, 2)
void g8(const u16* __restrict__ Ab, long sA,
        const u16* __restrict__ Bb, long sB,
        void* __restrict__ Cb, long sC,
        int grid_m, int grid_mn,
        int K, int lda, int ldb, int ldc, float scale,
        const u16* __restrict__ Mul, long sMul, int ldmul){
  __shared__ __align__(16) u16 S[65536];      // 128 KiB (2 dbufs)

  const int nwg = gridDim.x, orig = blockIdx.x;
  const int q = nwg >> 3, r = nwg & 7, xcd = orig & 7;
  const int wgid = (xcd < r ? xcd*(q+1) : r*(q+1) + (xcd - r)*q) + (orig >> 3);
  const int z   = wgid / grid_mn;
  const int rem = wgid - z*grid_mn;
  const int nb  = rem / grid_m;
  const int mb  = rem - nb*grid_m;
  const int m0 = mb*256, n0 = nb*256;
  const int tid = threadIdx.x, lane = tid & 63, wid = tid >> 6;

  if (EPI == 2 && n0 > m0 + 255) return;      // fully-masked causal block: skip

  const u16* A = Ab + (long)z*sA;
  const u16* B = Bb + (long)z*sB;

  const int rS = wid*16 + (lane >> 2);
  const int cS = (((lane & 3) ^ ((rS >> 1) & 3)) << 3);
  const u16* gA = A + (long)(m0 + rS)*lda + cS;
  const u16* gB = B + (long)(n0 + rS)*ldb + cS;

  char* Sb = (char*)&S[0];
  const unsigned db0 = 0, db1 = 65536u;
  auto issue = [&](const u16* src, unsigned dstOff){
    gload16(src, Sb + dstOff + (unsigned)wid*1024u);
  };

  const int wr = wid >> 2, wc = wid & 3;
  const int fr = lane & 15, fk = lane >> 4;
  const unsigned base = (unsigned)(unsigned long long)Sb;
  unsigned aOff[8], bOff[4];
  #pragma unroll
  for (int mi = 0; mi < 8; mi++){
    int row = wr*128 + mi*16 + fr;
    aOff[mi] = (unsigned)(row*64 + ((fk ^ ((row >> 1) & 3)) << 4));
  }
  #pragma unroll
  for (int ni = 0; ni < 4; ni++){
    int row = wc*64 + ni*16 + fr;
    bOff[ni] = 32768u + (unsigned)(row*64 + ((fk ^ ((row >> 1) & 3)) << 4));
  }

  const int NT = K >> 6;
  const int s0 = ((mb*3 + nb*5 + z)*7) % NT;  // stagger start tile
  const long lda128 = (long)128*lda, ldb128 = (long)128*ldb;

  f32x4 acc[8][4] = {};

  // prologue: physical tiles p0=s0 (both halves) -> db0, p1 (ks0) -> db1
  int p1 = s0 + 1; if (p1 >= NT) p1 -= NT;
  {
    const long kp0 = (long)s0*64, kp1 = (long)p1*64;
    issue(gA + kp0,            db0);          issue(gA + kp0 + lda128,      db0 + 8192u);
    issue(gB + kp0,            db0+32768u);   issue(gB + kp0 + ldb128,      db0 + 40960u);
    issue(gA + kp0 + 32,       db0+16384u);   issue(gA + kp0 + 32 + lda128, db0 + 24576u);
    issue(gB + kp0 + 32,       db0+49152u);   issue(gB + kp0 + 32 + ldb128, db0 + 57344u);
    issue(gA + kp1,            db1);          issue(gA + kp1 + lda128,      db1 + 8192u);
    issue(gB + kp1,            db1+32768u);   issue(gB + kp1 + ldb128,      db1 + 40960u);
  }
  asm volatile("s_waitcnt vmcnt(8)" ::: "memory");
  __builtin_amdgcn_s_barrier();
  __builtin_amdgcn_sched_barrier(0);

  int t1 = p1;                                 // physical index of logical t+1
  int t2 = p1 + 1; if (t2 >= NT) t2 -= NT;     // physical index of logical t+2
  for (int t = 0; t < NT; t++){
    const unsigned cur = (t & 1) ? db1 : db0;
    const unsigned oth = (t & 1) ? db0 : db1;
    const long k1 = (long)t1*64, k2 = (long)t2*64;
    const unsigned d1A = oth + 16384u, d1B = oth + 49152u;
    const unsigned d2A = cur,          d2B = cur + 32768u;
    bf16x8 a[4], b[4];

    // ---- ph0: (mh0, ks0) ----
    #pragma unroll
    for (int ni = 0; ni < 4; ni++) b[ni] = ldsr(base + cur + bOff[ni]);
    #pragma unroll
    for (int u = 0; u < 4; u++)    a[u]  = ldsr(base + cur + aOff[u]);
    issue(gA + k1 + 32, d1A); issue(gA + k1 + 32 + lda128, d1A + 8192u);
    __builtin_amdgcn_s_barrier();
    asm volatile("s_waitcnt lgkmcnt(0)" ::: "memory");
    __builtin_amdgcn_sched_barrier(0);
    __builtin_amdgcn_s_setprio(1);
    #pragma unroll
    for (int u = 0; u < 4; u++)
      #pragma unroll
      for (int ni = 0; ni < 4; ni++)
        acc[u][ni] = __builtin_amdgcn_mfma_f32_16x16x32_bf16(a[u], b[ni], acc[u][ni], 0, 0, 0);
    __builtin_amdgcn_s_setprio(0);
    __builtin_amdgcn_s_barrier();
    __builtin_amdgcn_sched_barrier(0);

    // ---- ph1: (mh1, ks0) ----
    #pragma unroll
    for (int u = 0; u < 4; u++) a[u] = ldsr(base + cur + aOff[4 + u]);
    issue(gB + k1 + 32, d1B); issue(gB + k1 + 32 + ldb128, d1B + 8192u);
    __builtin_amdgcn_s_barrier();
    asm volatile("s_waitcnt lgkmcnt(0)" ::: "memory");
    __builtin_amdgcn_sched_barrier(0);
    __builtin_amdgcn_s_setprio(1);
    #pragma unroll
    for (int u = 0; u < 4; u++)
      #pragma unroll
      for (int ni = 0; ni < 4; ni++)
        acc[4+u][ni] = __builtin_amdgcn_mfma_f32_16x16x32_bf16(a[u], b[ni], acc[4+u][ni], 0, 0, 0);
    __builtin_amdgcn_s_setprio(0);
    asm volatile("s_waitcnt vmcnt(8)" ::: "memory");
    __builtin_amdgcn_s_barrier();
    __builtin_amdgcn_sched_barrier(0);

    // ---- ph2: (mh0, ks1) ----
    #pragma unroll
    for (int ni = 0; ni < 4; ni++) b[ni] = ldsr(base + cur + bOff[ni] + 16384u);
    #pragma unroll
    for (int u = 0; u < 4; u++)    a[u]  = ldsr(base + cur + aOff[u] + 16384u);
    issue(gA + k2, d2A); issue(gA + k2 + lda128, d2A + 8192u);
    __builtin_amdgcn_s_barrier();
    asm volatile("s_waitcnt lgkmcnt(0)" ::: "memory");
    __builtin_amdgcn_sched_barrier(0);
    __builtin_amdgcn_s_setprio(1);
    #pragma unroll
    for (int u = 0; u < 4; u++)
      #pragma unroll
      for (int ni = 0; ni < 4; ni++)
        acc[u][ni] = __builtin_amdgcn_mfma_f32_16x16x32_bf16(a[u], b[ni], acc[u][ni], 0, 0, 0);
    __builtin_amdgcn_s_setprio(0);
    __builtin_amdgcn_s_barrier();
    __builtin_amdgcn_sched_barrier(0);

    // ---- ph3: (mh1, ks1) ----
    #pragma unroll
    for (int u = 0; u < 4; u++) a[u] = ldsr(base + cur + aOff[4 + u] + 16384u);
    issue(gB + k2, d2B); issue(gB + k2 + ldb128, d2B + 8192u);
    __builtin_amdgcn_s_barrier();
    asm volatile("s_waitcnt lgkmcnt(0)" ::: "memory");
    __builtin_amdgcn_sched_barrier(0);
    __builtin_amdgcn_s_setprio(1);
    #pragma unroll
    for (int u = 0; u < 4; u++)
      #pragma unroll
      for (int ni = 0; ni < 4; ni++)
        acc[4+u][ni] = __builtin_amdgcn_mfma_f32_16x16x32_bf16(a[u], b[ni], acc[4+u][ni], 0, 0, 0);
    __builtin_amdgcn_s_setprio(0);
    asm volatile("s_waitcnt vmcnt(8)" ::: "memory");
    __builtin_amdgcn_s_barrier();
    __builtin_amdgcn_sched_barrier(0);

    t1 = t2;
    t2 = t2 + 1; if (t2 >= NT) t2 -= NT;
  }
  asm volatile("s_waitcnt vmcnt(0)" ::: "memory");     // drain wrapped tail stages

  const int er = (lane >> 4) * 4, ec = lane & 15;
  #pragma unroll
  for (int mi = 0; mi < 8; mi++){
    #pragma unroll
    for (int ni = 0; ni < 4; ni++){
      #pragma unroll
      for (int j = 0; j < 4; j++){
        int row = m0 + wr*128 + mi*16 + er + j;
        int col = n0 + wc*64 + ni*16 + ec;
        float v = acc[mi][ni][j];
        if (EPI == 0){
          ((float*)Cb + (long)z * sC)[(long)row * ldc + col] = v;
        } else if (EPI == 1){
          v = v > 0.f ? v : 0.f;
          ((u16*)Cb + (long)z * sC)[(long)row * ldc + col] = f2b(v);
        } else if (EPI == 2){
          ((u16*)Cb + (long)z * sC)[(long)row * ldc + col] = f2b(v * scale);
        } else {
          v = v > 0.f ? v : 0.f;
          float mfv = b2f((Mul + (long)z * sMul)[(long)row * ldmul + col]);
          ((u16*)Cb + (long)z * sC)[(long)row * ldc + col] = f2b(v * mfv);
        }
      }
    }
  }
}

// ==========================================================================
// gemmw: 128x256 (unchanged verified structure). EPI 0=f32 | 4=bf16 raw
// CCLAMP: K clamped to m0+128 (causal attn.V)
// ==========================================================================
template<int EPI, bool CCLAMP>
__global__ __launch_bounds__(256, 2)
void gemmw(const u16* __restrict__ Ab, long sA,
           const u16* __restrict__ Bb, long sB,
           void* __restrict__ Cb, long sC,
           int grid_m, int grid_mn,
           int K, int lda, int ldb, int ldc){
  constexpr unsigned BUFB = 24576u;
  __shared__ __align__(16) u16 S[3 * 12288];

  const int nwg = gridDim.x, orig = blockIdx.x;
  const int q = nwg >> 3, r = nwg & 7, xcd = orig & 7;
  const int wgid = (xcd < r ? xcd*(q+1) : r*(q+1) + (xcd - r)*q) + (orig >> 3);
  const int z   = wgid / grid_mn;
  const int rem = wgid - z*grid_mn;
  const int nb  = rem / grid_m;
  const int mb  = rem - nb*grid_m;
  const int m0 = mb*128, n0 = nb*256;
  const int tid = threadIdx.x, lane = tid & 63, wid = tid >> 6;

  const u16* A = Ab + (long)z*sA;
  const u16* B = Bb + (long)z*sB;

  const int rS = tid >> 2;
  const int cS = (((tid & 3) ^ ((rS >> 1) & 3)) << 3);
  const u16* gA[2]; const u16* gB[4];
  #pragma unroll
  for (int i = 0; i < 2; i++) gA[i] = A + (long)(m0 + i*64 + rS)*lda + cS;
  #pragma unroll
  for (int i = 0; i < 4; i++) gB[i] = B + (long)(n0 + i*64 + rS)*ldb + cS;

  char* Sb = (char*)&S[0];
  auto stage = [&](int kt, unsigned bB){
    const int ko = kt << 5;
    gload16(gA[0] + ko, Sb + bB +          wid*1024u);
    gload16(gA[1] + ko, Sb + bB +  4096u + wid*1024u);
    #pragma unroll
    for (int i = 0; i < 4; i++)
      gload16(gB[i] + ko, Sb + bB + 8192u + i*4096u + wid*1024u);
  };

  const int wr = wid >> 1, wc = wid & 1;
  const int fr = lane & 15, fk = lane >> 4;
  const unsigned base = (unsigned)(unsigned long long)Sb;
  unsigned aAd[4], bAd[8];
  #pragma unroll
  for (int mi = 0; mi < 4; mi++){
    int row = wr*64 + mi*16 + fr;
    aAd[mi] = base + (unsigned)(row*64 + ((fk ^ ((row >> 1) & 3)) << 4));
  }
  #pragma unroll
  for (int ni = 0; ni < 8; ni++){
    int row = wc*128 + ni*16 + fr;
    bAd[ni] = base + 8192u + (unsigned)(row*64 + ((fk ^ ((row >> 1) & 3)) << 4));
  }

  const int Keff = CCLAMP ? (m0 + 128 < K ? m0 + 128 : K) : K;
  const int NT = Keff >> 5;
  const int s0 = (mb*13 + nb*7 + z*5) % NT;

  f32x4 acc[4][8] = {};

  int p1 = s0 + 1; if (p1 >= NT) p1 -= NT;
  stage(s0, 0);
  stage(p1, BUFB);
  asm volatile("s_waitcnt vmcnt(6)" ::: "memory");
  __builtin_amdgcn_s_barrier();
  __builtin_amdgcn_sched_barrier(0);

  unsigned rbB = 0, wbB = 2u*BUFB;
  for (int t = 0; t < NT; t++){
    int nx = (t + 2 < NT) ? t + 2 : NT - 1;
    int ph = s0 + nx; if (ph >= NT) ph -= NT;
    stage(ph, wbB);
    bf16x8 afr[4], bfr[8];
    #pragma unroll
    for (int ni = 0; ni < 8; ni++) bfr[ni] = ldsr(bAd[ni] + rbB);
    #pragma unroll
    for (int mi = 0; mi < 4; mi++) afr[mi] = ldsr(aAd[mi] + rbB);
    __builtin_amdgcn_s_barrier();
    asm volatile("s_waitcnt lgkmcnt(0)" ::: "memory");
    __builtin_amdgcn_sched_barrier(0);
    __builtin_amdgcn_s_setprio(1);
    #pragma unroll
    for (int mi = 0; mi < 4; mi++)
      #pragma unroll
      for (int ni = 0; ni < 8; ni++)
        acc[mi][ni] = __builtin_amdgcn_mfma_f32_16x16x32_bf16(afr[mi], bfr[ni], acc[mi][ni], 0, 0, 0);
    __builtin_amdgcn_s_setprio(0);
    __builtin_amdgcn_sched_barrier(0);
    asm volatile("s_waitcnt vmcnt(6)" ::: "memory");
    __builtin_amdgcn_s_barrier();
    __builtin_amdgcn_sched_barrier(0);
    unsigned tmp = rbB; rbB += BUFB; if (rbB == 3u*BUFB) rbB = 0;
    wbB = tmp;
  }
  asm volatile("s_waitcnt vmcnt(0)" ::: "memory");

  const int er = (lane >> 4) * 4, ec = lane & 15;
  #pragma unroll
  for (int mi = 0; mi < 4; mi++){
    #pragma unroll
    for (int ni = 0; ni < 8; ni++){
      #pragma unroll
      for (int j = 0; j < 4; j++){
        int row = m0 + wr*64 + mi*16 + er + j;
        int col = n0 + wc*128 + ni*16 + ec;
        float v = acc[mi][ni][j];
        if (EPI == 0){
          ((float*)Cb + (long)z * sC)[(long)row * ldc + col] = v;
        } else {
          ((u16*)Cb + (long)z * sC)[(long)row * ldc + col] = f2b(v);
        }
      }
    }
  }
}

// ---------- host ----------
extern "C" void kernel_launch(void* const* d_in, const int* in_sizes, int n_in,
                              void* d_out, int out_size, void* d_ws, size_t ws_size,
                              hipStream_t stream){
  (void)in_sizes; (void)n_in; (void)out_size; (void)ws_size;
  const int*   idx     = (const int*)  d_in[0];
  const float* embed   = (const float*)d_in[1];
  const float* encoder = (const float*)d_in[2];
  const float* encv    = (const float*)d_in[3];
  const float* decoder = (const float*)d_in[4];
  const float* lm_head = (const float*)d_in[5];
  const float* ln_w    = (const float*)d_in[6];
  const float* ln_b    = (const float*)d_in[7];
  float* out = (float*)d_out;

  char* p = (char*)d_ws;
  auto take = [&](size_t n){ char* r = p; p += (n + 255) & ~(size_t)255; return r; };
  u16*   encT  = (u16*)  take((size_t)NHH * ND * EE * 2);
  u16*   encvT = (u16*)  take((size_t)NHH * ND * EE * 2);
  u16*   decT  = (u16*)  take((size_t)EE * HNN * 2);
  u16*   lmhB  = (u16*)  take((size_t)VOC * EE * 2);
  float* xf    = (float*)take((size_t)TT * EE * 4);
  u16*   xb    = (u16*)  take((size_t)TT * EE * 2);
  u16*   xT    = (u16*)  take((size_t)EE * TT * 2);
  u16*   xs    = (u16*)  take((size_t)NHH * TT * ND * 2);
  char*  big   =         take((size_t)NHH * TT * TT * 4);
  u16*   attn  = (u16*)  take((size_t)NHH * TT * TT * 2);   // dead after attn.V
  u16*   yb    = (u16*)  take((size_t)NHH * TT * EE * 2);
  take((size_t)8 * TT * EE * 4);
  u16*   scores = (u16*)big;
  u16*   ybig   = (u16*)big;
  u16*   xy     = (u16*)big;
  u16*   part   = attn;    // SPLITK bf16 partials overlay dead attn

  dim3 blk(256, 1, 1);

  prep<<<dim3(79296, 1, 1), blk, 0, stream>>>(encoder, encv, decoder, lm_head,
                                              encT, encvT, decT, lmhB);

  embed_ln<<<dim3(TT, 1, 1), blk, 0, stream>>>(idx, embed, ln_w, ln_b, xf, xb);
  xpose<<<dim3(EE / 64, TT / 64, 1), blk, 0, stream>>>(xb, xT);

  const float scl = 0.022097086912079608f;  // 1/sqrt(2048)

  for (int L = 0; L < NLAYER; ++L){
    // x_sparse[h] = relu(x @ enc[h])  -> bf16 [H][T][N]
    g8<1><<<dim3(4*8*NHH), dim3(512), 0, stream>>>(
        xb, 0, encT, (long)ND * EE, xs, (long)TT * ND,
        4, 32, EE, EE, EE, ND, 0.f, (const u16*)0, 0, 0);
    // scores[h] = scale * xs[h] @ xs[h]^T -> BF16 [H][T][T] (masked blocks skipped)
    g8<2><<<dim3(4*4*NHH), dim3(512), 0, stream>>>(
        xs, (long)TT * ND, xs, (long)TT * ND, scores, (long)TT * TT,
        4, 16, ND, ND, ND, TT, scl, (const u16*)0, 0, 0);
    softmax_rows<<<dim3(TT, NHH, 1), blk, 0, stream>>>(scores, attn);
    // y[h] = attn[h] @ x  -> BF16 [H][T][E]  (causal K-clamp; overlays dead scores)
    gemmw<4,true><<<dim3(8*3*NHH), blk, 0, stream>>>(
        attn, (long)TT * TT, xT, 0, ybig, (long)TT * EE,
        8, 24, TT, TT, TT, EE);
    ln_rows<<<dim3(NHH * TT, 1, 1), blk, 0, stream>>>(ybig, yb, ln_w, ln_b);
    // xy[t][h*N+n] = relu(y[h] @ encv[h]) * xs[h]  -> bf16 [T][H*N]
    g8<3><<<dim3(4*8*NHH), dim3(512), 0, stream>>>(
        yb, (long)TT * EE, encvT, (long)ND * EE, xy, (long)ND,
        4, 32, EE, EE, EE, HNN, 0.f, xs, (long)TT * ND, ND);
    // y_mlp partials (bf16): split-K over 24576 (SPLITK=16 chunks of 1536)
    gemmw<4,false><<<dim3(8*3*SPLITK), blk, 0, stream>>>(
        xy, (long)(HNN / SPLITK), decT, (long)(HNN / SPLITK), part, (long)TT * EE,
        8, 24, HNN / SPLITK, HNN, HNN, EE);
    residual_ln<SPLITK><<<dim3(TT, 1, 1), blk, 0, stream>>>(part, xf, xf, xb, ln_w, ln_b);
    xpose<<<dim3(EE / 64, TT / 64, 1), blk, 0, stream>>>(xb, xT);
  }

  // logits = x @ lm_head^T -> f32 [T][V]
  g8<0><<<dim3(4*125), dim3(512), 0, stream>>>(
      xb, 0, lmhB, 0, out, 0,
      4, 500, EE, EE, EE, VOC, 0.f, (const u16*)0, 0, 0);
}

// Round 13
// 1896.974 us; speedup vs baseline: 1.0276x; 1.0276x over previous
//
#include <hip/hip_runtime.h>

typedef unsigned short u16;
typedef short bf16x8 __attribute__((ext_vector_type(8)));
typedef float f32x4 __attribute__((ext_vector_type(4)));
typedef u16 u16x4 __attribute__((ext_vector_type(4)));

#define TT     1024
#define EE     768
#define NHH    12
#define ND     2048
#define VOC    32000
#define HNN    24576
#define NLAYER 6
#define LN_EPS 1e-5f
#define SPLITK 16

// ---------- bf16 helpers ----------
__device__ __forceinline__ float b2f(u16 u){
  unsigned int x = ((unsigned int)u) << 16; float f; __builtin_memcpy(&f, &x, 4); return f;
}
__device__ __forceinline__ u16 f2b(float f){
  unsigned int x; __builtin_memcpy(&x, &f, 4);
  x = x + 0x7fffu + ((x >> 16) & 1u);
  return (u16)(x >> 16);
}

__device__ __forceinline__ void gload16(const void* g, void* lds){
  __builtin_amdgcn_global_load_lds(
      (const __attribute__((address_space(1))) unsigned int*)g,
      (__attribute__((address_space(3))) unsigned int*)(unsigned int)(unsigned long long)lds,
      16, 0, 0);
}

__device__ __forceinline__ bf16x8 ldsr(unsigned addr){
  bf16x8 r;
  asm volatile("ds_read_b128 %0, %1" : "=v"(r) : "v"(addr));
  return r;
}

// ---------- block reductions (256 threads = 4 waves) ----------
__device__ __forceinline__ void blk_sum2(float& a, float& b){
  #pragma unroll
  for (int o = 32; o > 0; o >>= 1){ a += __shfl_down(a, o); b += __shfl_down(b, o); }
  __shared__ float sa[4], sb[4];
  int lane = threadIdx.x & 63, wid = threadIdx.x >> 6;
  __syncthreads();
  if (lane == 0){ sa[wid] = a; sb[wid] = b; }
  __syncthreads();
  a = (sa[0] + sa[1]) + (sa[2] + sa[3]);
  b = (sb[0] + sb[1]) + (sb[2] + sb[3]);
}
__device__ __forceinline__ float blk_max(float v){
  #pragma unroll
  for (int o = 32; o > 0; o >>= 1) v = fmaxf(v, __shfl_down(v, o));
  __shared__ float sm[4];
  int lane = threadIdx.x & 63, wid = threadIdx.x >> 6;
  __syncthreads();
  if (lane == 0) sm[wid] = v;
  __syncthreads();
  return fmaxf(fmaxf(sm[0], sm[1]), fmaxf(sm[2], sm[3]));
}
__device__ __forceinline__ float blk_sum(float v){
  #pragma unroll
  for (int o = 32; o > 0; o >>= 1) v += __shfl_down(v, o);
  __shared__ float ss[4];
  int lane = threadIdx.x & 63, wid = threadIdx.x >> 6;
  __syncthreads();
  if (lane == 0) ss[wid] = v;
  __syncthreads();
  return (ss[0] + ss[1]) + (ss[2] + ss[3]);
}

// ---------- merged weight preprocessing, 64x64 tiles ----------
// reads f32x4 (256B/row), writes u16x4 (128B/row); LDS [64][65] (2-way free)
__global__ void prep(const float* __restrict__ enc, const float* __restrict__ encv,
                     const float* __restrict__ dec, const float* __restrict__ lmh,
                     u16* __restrict__ encT, u16* __restrict__ encvT,
                     u16* __restrict__ decT, u16* __restrict__ lmhB){
  __shared__ float tile[64][65];
  int b = blockIdx.x;
  int lx = threadIdx.x & 15, ly = threadIdx.x >> 4;   // 16 x 16
  if (b < 9216){
    // enc/encv: in [E][ND] per head -> out [ND][E]
    const float* in; u16* out;
    if (b < 4608){ in = enc; out = encT; } else { in = encv; out = encvT; b -= 4608; }
    int z = b / 384, rem = b - z * 384;
    int r0 = (rem >> 5) * 64;                // over EE (12 tiles)
    int c0 = (rem & 31) * 64;                // over ND (32 tiles)
    in  += (long)z * EE * ND;
    out += (long)z * ND * EE;
    #pragma unroll
    for (int i = 0; i < 4; i++){
      float4 v = *(const float4*)&in[(long)(r0 + ly + i*16) * ND + c0 + lx*4];
      tile[lx*4+0][ly+i*16] = v.x; tile[lx*4+1][ly+i*16] = v.y;
      tile[lx*4+2][ly+i*16] = v.z; tile[lx*4+3][ly+i*16] = v.w;
    }
    __syncthreads();
    #pragma unroll
    for (int i = 0; i < 4; i++){
      int crow = ly + i*16;
      u16x4 o;
      #pragma unroll
      for (int j = 0; j < 4; j++) o[j] = f2b(tile[crow][lx*4+j]);
      *(u16x4*)&out[(long)(c0 + crow) * EE + r0 + lx*4] = o;
    }
  } else if (b < 13824){
    // dec: [HNN][E] -> decT [E][HNN]
    b -= 9216;
    int r0 = (b / 12) * 64;                  // over HNN (384 tiles)
    int c0 = (b % 12) * 64;                  // over EE (12 tiles)
    #pragma unroll
    for (int i = 0; i < 4; i++){
      float4 v = *(const float4*)&dec[(long)(r0 + ly + i*16) * EE + c0 + lx*4];
      tile[lx*4+0][ly+i*16] = v.x; tile[lx*4+1][ly+i*16] = v.y;
      tile[lx*4+2][ly+i*16] = v.z; tile[lx*4+3][ly+i*16] = v.w;
    }
    __syncthreads();
    #pragma unroll
    for (int i = 0; i < 4; i++){
      int crow = ly + i*16;
      u16x4 o;
      #pragma unroll
      for (int j = 0; j < 4; j++) o[j] = f2b(tile[crow][lx*4+j]);
      *(u16x4*)&decT[(long)(c0 + crow) * HNN + r0 + lx*4] = o;
    }
  } else {
    b -= 13824;                              // lm_head f32 -> bf16 copy (24000 blocks)
    long i = ((long)b * 256 + threadIdx.x) * 4;
    float4 v = *(const float4*)(lmh + i);
    u16x4 o; o.x = f2b(v.x); o.y = f2b(v.y); o.z = f2b(v.z); o.w = f2b(v.w);
    *(u16x4*)(lmhB + i) = o;
  }
}

// ---------- coalesced bf16 transpose: xT[e][t] = xb[t][e] ----------
__global__ void xpose(const u16* __restrict__ in, u16* __restrict__ out){
  __shared__ u16 t[64][65];
  int e0 = blockIdx.x * 64, t0 = blockIdx.y * 64;
  int lx = threadIdx.x & 63, ly = threadIdx.x >> 6;   // 64 x 4
  #pragma unroll
  for (int i = 0; i < 64; i += 4)
    t[ly + i][lx] = in[(long)(t0 + ly + i) * EE + e0 + lx];
  __syncthreads();
  #pragma unroll
  for (int i = 0; i < 64; i += 4)
    out[(long)(e0 + ly + i) * TT + t0 + lx] = t[lx][ly + i];
}

// ---------- embed gather + LN (vectorized: 192 threads x float4) ----------
__global__ void embed_ln(const int* __restrict__ idx, const float* __restrict__ emb,
                         const float* __restrict__ w, const float* __restrict__ b,
                         float* __restrict__ xf, u16* __restrict__ xb){
  int t = blockIdx.x, tid = threadIdx.x;
  const float* src = emb + (long)idx[t] * EE;
  float v[4] = {0.f, 0.f, 0.f, 0.f};
  if (tid < 192){
    float4 r = *(const float4*)&src[tid * 4];
    v[0] = r.x; v[1] = r.y; v[2] = r.z; v[3] = r.w;
  }
  float s = (v[0] + v[1]) + (v[2] + v[3]);
  float s2 = (v[0]*v[0] + v[1]*v[1]) + (v[2]*v[2] + v[3]*v[3]);
  blk_sum2(s, s2);
  float m  = s * (1.0f / EE);
  float var = s2 * (1.0f / EE) - m * m;
  float rs = rsqrtf(var + LN_EPS);
  if (tid < 192){
    int e0 = tid * 4;
    float4 o; u16x4 ob;
    float* op = &o.x;
    #pragma unroll
    for (int j = 0; j < 4; j++){
      float ov = (v[j] - m) * rs * w[e0 + j] + b[e0 + j];
      op[j] = ov; ob[j] = f2b(ov);
    }
    *(float4*)&xf[(long)t * EE + e0] = o;
    *(u16x4*)&xb[(long)t * EE + e0] = ob;
  }
}

// ---------- row LN, bf16 in -> bf16 out (vectorized) ----------
__global__ void ln_rows(const u16* __restrict__ in, u16* __restrict__ out,
                        const float* __restrict__ w, const float* __restrict__ b){
  long row = blockIdx.x; int tid = threadIdx.x;
  const u16* src = in + row * EE;
  float v[4] = {0.f, 0.f, 0.f, 0.f};
  if (tid < 192){
    u16x4 r = *(const u16x4*)&src[tid * 4];
    #pragma unroll
    for (int j = 0; j < 4; j++) v[j] = b2f(r[j]);
  }
  float s = (v[0] + v[1]) + (v[2] + v[3]);
  float s2 = (v[0]*v[0] + v[1]*v[1]) + (v[2]*v[2] + v[3]*v[3]);
  blk_sum2(s, s2);
  float m = s * (1.0f / EE);
  float var = s2 * (1.0f / EE) - m * m;
  float rs = rsqrtf(var + LN_EPS);
  if (tid < 192){
    int e0 = tid * 4;
    u16x4 ob;
    #pragma unroll
    for (int j = 0; j < 4; j++) ob[j] = f2b((v[j] - m) * rs * w[e0 + j] + b[e0 + j]);
    *(u16x4*)&out[row * EE + e0] = ob;
  }
}

// ---------- softmax, causal prefix only, bf16 in/out, vectorized ----------
__global__ void softmax_rows(const u16* __restrict__ scores, u16* __restrict__ attn){
  int q = blockIdx.x, h = blockIdx.y, tid = threadIdx.x;
  const u16* srow = scores + ((long)h * TT + q) * TT;
  u16* arow = attn + ((long)h * TT + q) * TT;
  const int len = q + 1;
  const int pad = (q + 128) & ~127;
  u16x4 raw = *(const u16x4*)&srow[tid * 4];
  float v[4];
  float mx = -1e30f;
  #pragma unroll
  for (int j = 0; j < 4; j++){
    int i = tid * 4 + j;
    v[j] = (i < len) ? b2f(raw[j]) : -1e30f;
    mx = fmaxf(mx, v[j]);
  }
  mx = blk_max(mx);
  float s = 0.f;
  #pragma unroll
  for (int j = 0; j < 4; j++){
    int i = tid * 4 + j;
    float e = (i < len) ? __expf(v[j] - mx) : 0.f;
    v[j] = e; s += e;
  }
  float inv = 1.0f / blk_sum(s);
  int i0 = tid * 4;
  if (i0 < pad){
    u16x4 o;
    #pragma unroll
    for (int j = 0; j < 4; j++) o[j] = (i0 + j < len) ? f2b(v[j] * inv) : (u16)0;
    *(u16x4*)&arow[i0] = o;
  }
}

// ---------- residual: x = ln(x + ln(sum_p part_p)), part bf16, vectorized ----------
template<int P>
__global__ void residual_ln(const u16* __restrict__ part, const float* __restrict__ xin,
                            float* __restrict__ xf, u16* __restrict__ xb,
                            const float* __restrict__ w, const float* __restrict__ b){
  int t = blockIdx.x, tid = threadIdx.x;
  float g[4] = {0.f, 0.f, 0.f, 0.f};
  if (tid < 192){
    int e0 = tid * 4;
    #pragma unroll
    for (int pp = 0; pp < P; pp++){
      u16x4 r = *(const u16x4*)&part[((long)pp * TT + t) * EE + e0];
      #pragma unroll
      for (int j = 0; j < 4; j++) g[j] += b2f(r[j]);
    }
  }
  float s = (g[0] + g[1]) + (g[2] + g[3]);
  float s2 = (g[0]*g[0] + g[1]*g[1]) + (g[2]*g[2] + g[3]*g[3]);
  blk_sum2(s, s2);
  float m = s * (1.0f / EE), var = s2 * (1.0f / EE) - m * m;
  float rs = rsqrtf(var + LN_EPS);
  float hh[4] = {0.f, 0.f, 0.f, 0.f};
  if (tid < 192){
    int e0 = tid * 4;
    float4 xi = *(const float4*)&xin[(long)t * EE + e0];
    const float* xp = &xi.x;
    #pragma unroll
    for (int j = 0; j < 4; j++)
      hh[j] = xp[j] + ((g[j] - m) * rs * w[e0 + j] + b[e0 + j]);
  }
  s = (hh[0] + hh[1]) + (hh[2] + hh[3]);
  s2 = (hh[0]*hh[0] + hh[1]*hh[1]) + (hh[2]*hh[2] + hh[3]*hh[3]);
  blk_sum2(s, s2);
  m = s * (1.0f / EE); var = s2 * (1.0f / EE) - m * m; rs = rsqrtf(var + LN_EPS);
  if (tid < 192){
    int e0 = tid * 4;
    float4 o; u16x4 ob;
    float* op = &o.x;
    #pragma unroll
    for (int j = 0; j < 4; j++){
      float ov = (hh[j] - m) * rs * w[e0 + j] + b[e0 + j];
      op[j] = ov; ob[j] = f2b(ov);
    }
    *(float4*)&xf[(long)t * EE + e0] = o;
    *(u16x4*)&xb[(long)t * EE + e0] = ob;
  }
}

// ==========================================================================
// g8: 256x256 8-phase NT GEMM — r11 verified schedule (NO K-stagger;
// sequential K, scratch-region tail keeps vmcnt uniform).
// EPI: 0=f32 | 1=relu->bf16 | 2=*scale->bf16 (causal skip) | 3=relu*Mul->bf16
// ==========================================================================
template<int EPI>
__global__ __launch_bounds__(512, 2)
void g8(const u16* __restrict__ Ab, long sA,
        const u16* __restrict__ Bb, long sB,
        void* __restrict__ Cb, long sC,
        int grid_m, int grid_mn,
        int K, int lda, int ldb, int ldc, float scale,
        const u16* __restrict__ Mul, long sMul, int ldmul){
  __shared__ __align__(16) u16 S[69632];      // 136 KiB (2 dbufs + scratch)

  const int nwg = gridDim.x, orig = blockIdx.x;
  const int q = nwg >> 3, r = nwg & 7, xcd = orig & 7;
  const int wgid = (xcd < r ? xcd*(q+1) : r*(q+1) + (xcd - r)*q) + (orig >> 3);
  const int z   = wgid / grid_mn;
  const int rem = wgid - z*grid_mn;
  const int nb  = rem / grid_m;
  const int mb  = rem - nb*grid_m;
  const int m0 = mb*256, n0 = nb*256;
  const int tid = threadIdx.x, lane = tid & 63, wid = tid >> 6;

  if (EPI == 2 && n0 > m0 + 255) return;      // fully-masked causal block: skip

  const u16* A = Ab + (long)z*sA;
  const u16* B = Bb + (long)z*sB;

  const int rS = wid*16 + (lane >> 2);
  const int cS = (((lane & 3) ^ ((rS >> 1) & 3)) << 3);
  const u16* gA = A + (long)(m0 + rS)*lda + cS;
  const u16* gB = B + (long)(n0 + rS)*ldb + cS;

  char* Sb = (char*)&S[0];
  const unsigned db0 = 0, db1 = 65536u, scr = 131072u;
  auto issue = [&](const u16* src, unsigned dstOff){
    gload16(src, Sb + dstOff + (unsigned)wid*1024u);
  };

  const int wr = wid >> 2, wc = wid & 3;
  const int fr = lane & 15, fk = lane >> 4;
  const unsigned base = (unsigned)(unsigned long long)Sb;
  unsigned aOff[8], bOff[4];
  #pragma unroll
  for (int mi = 0; mi < 8; mi++){
    int row = wr*128 + mi*16 + fr;
    aOff[mi] = (unsigned)(row*64 + ((fk ^ ((row >> 1) & 3)) << 4));
  }
  #pragma unroll
  for (int ni = 0; ni < 4; ni++){
    int row = wc*64 + ni*16 + fr;
    bOff[ni] = 32768u + (unsigned)(row*64 + ((fk ^ ((row >> 1) & 3)) << 4));
  }

  const int NT = K >> 6;
  const long lda128 = (long)128*lda, ldb128 = (long)128*ldb;

  f32x4 acc[8][4] = {};

  issue(gA,              db0);          issue(gA + lda128,          db0 + 8192u);
  issue(gB,              db0+32768u);   issue(gB + ldb128,          db0 + 40960u);
  issue(gA + 32,         db0+16384u);   issue(gA + 32 + lda128,     db0 + 24576u);
  issue(gB + 32,         db0+49152u);   issue(gB + 32 + ldb128,     db0 + 57344u);
  issue(gA + 64,         db1);          issue(gA + 64 + lda128,     db1 + 8192u);
  issue(gB + 64,         db1+32768u);   issue(gB + 64 + ldb128,     db1 + 40960u);
  asm volatile("s_waitcnt vmcnt(8)" ::: "memory");
  __builtin_amdgcn_s_barrier();
  __builtin_amdgcn_sched_barrier(0);

  for (int t = 0; t < NT; t++){
    const unsigned cur = (t & 1) ? db1 : db0;
    const unsigned oth = (t & 1) ? db0 : db1;
    const bool v1 = (t + 1 < NT), v2 = (t + 2 < NT);
    const long k1 = (long)(v1 ? t + 1 : 0) * 64;
    const long k2 = (long)(v2 ? t + 2 : 0) * 64;
    const unsigned d1A = v1 ? oth + 16384u : scr;
    const unsigned d1B = v1 ? oth + 49152u : scr;
    const unsigned d2A = v2 ? cur           : scr;
    const unsigned d2B = v2 ? cur + 32768u  : scr;
    bf16x8 a[4], b[4];

    // ---- ph0: (mh0, ks0) ----
    #pragma unroll
    for (int ni = 0; ni < 4; ni++) b[ni] = ldsr(base + cur + bOff[ni]);
    #pragma unroll
    for (int u = 0; u < 4; u++)    a[u]  = ldsr(base + cur + aOff[u]);
    issue(gA + k1 + 32, d1A); issue(gA + k1 + 32 + lda128, d1A + 8192u);
    __builtin_amdgcn_s_barrier();
    asm volatile("s_waitcnt lgkmcnt(0)" ::: "memory");
    __builtin_amdgcn_sched_barrier(0);
    __builtin_amdgcn_s_setprio(1);
    #pragma unroll
    for (int u = 0; u < 4; u++)
      #pragma unroll
      for (int ni = 0; ni < 4; ni++)
        acc[u][ni] = __builtin_amdgcn_mfma_f32_16x16x32_bf16(a[u], b[ni], acc[u][ni], 0, 0, 0);
    __builtin_amdgcn_s_setprio(0);
    __builtin_amdgcn_s_barrier();
    __builtin_amdgcn_sched_barrier(0);

    // ---- ph1: (mh1, ks0) ----
    #pragma unroll
    for (int u = 0; u < 4; u++) a[u] = ldsr(base + cur + aOff[4 + u]);
    issue(gB + k1 + 32, d1B); issue(gB + k1 + 32 + ldb128, d1B + 8192u);
    __builtin_amdgcn_s_barrier();
    asm volatile("s_waitcnt lgkmcnt(0)" ::: "memory");
    __builtin_amdgcn_sched_barrier(0);
    __builtin_amdgcn_s_setprio(1);
    #pragma unroll
    for (int u = 0; u < 4; u++)
      #pragma unroll
      for (int ni = 0; ni < 4; ni++)
        acc[4+u][ni] = __builtin_amdgcn_mfma_f32_16x16x32_bf16(a[u], b[ni], acc[4+u][ni], 0, 0, 0);
    __builtin_amdgcn_s_setprio(0);
    asm volatile("s_waitcnt vmcnt(8)" ::: "memory");
    __builtin_amdgcn_s_barrier();
    __builtin_amdgcn_sched_barrier(0);

    // ---- ph2: (mh0, ks1) ----
    #pragma unroll
    for (int ni = 0; ni < 4; ni++) b[ni] = ldsr(base + cur + bOff[ni] + 16384u);
    #pragma unroll
    for (int u = 0; u < 4; u++)    a[u]  = ldsr(base + cur + aOff[u] + 16384u);
    issue(gA + k2, d2A); issue(gA + k2 + lda128, d2A + 8192u);
    __builtin_amdgcn_s_barrier();
    asm volatile("s_waitcnt lgkmcnt(0)" ::: "memory");
    __builtin_amdgcn_sched_barrier(0);
    __builtin_amdgcn_s_setprio(1);
    #pragma unroll
    for (int u = 0; u < 4; u++)
      #pragma unroll
      for (int ni = 0; ni < 4; ni++)
        acc[u][ni] = __builtin_amdgcn_mfma_f32_16x16x32_bf16(a[u], b[ni], acc[u][ni], 0, 0, 0);
    __builtin_amdgcn_s_setprio(0);
    __builtin_amdgcn_s_barrier();
    __builtin_amdgcn_sched_barrier(0);

    // ---- ph3: (mh1, ks1) ----
    #pragma unroll
    for (int u = 0; u < 4; u++) a[u] = ldsr(base + cur + aOff[4 + u] + 16384u);
    issue(gB + k2, d2B); issue(gB + k2 + ldb128, d2B + 8192u);
    __builtin_amdgcn_s_barrier();
    asm volatile("s_waitcnt lgkmcnt(0)" ::: "memory");
    __builtin_amdgcn_sched_barrier(0);
    __builtin_amdgcn_s_setprio(1);
    #pragma unroll
    for (int u = 0; u < 4; u++)
      #pragma unroll
      for (int ni = 0; ni < 4; ni++)
        acc[4+u][ni] = __builtin_amdgcn_mfma_f32_16x16x32_bf16(a[u], b[ni], acc[4+u][ni], 0, 0, 0);
    __builtin_amdgcn_s_setprio(0);
    asm volatile("s_waitcnt vmcnt(8)" ::: "memory");
    __builtin_amdgcn_s_barrier();
    __builtin_amdgcn_sched_barrier(0);
  }
  asm volatile("s_waitcnt vmcnt(0)" ::: "memory");

  const int er = (lane >> 4) * 4, ec = lane & 15;
  #pragma unroll
  for (int mi = 0; mi < 8; mi++){
    #pragma unroll
    for (int ni = 0; ni < 4; ni++){
      #pragma unroll
      for (int j = 0; j < 4; j++){
        int row = m0 + wr*128 + mi*16 + er + j;
        int col = n0 + wc*64 + ni*16 + ec;
        float v = acc[mi][ni][j];
        if (EPI == 0){
          ((float*)Cb + (long)z * sC)[(long)row * ldc + col] = v;
        } else if (EPI == 1){
          v = v > 0.f ? v : 0.f;
          ((u16*)Cb + (long)z * sC)[(long)row * ldc + col] = f2b(v);
        } else if (EPI == 2){
          ((u16*)Cb + (long)z * sC)[(long)row * ldc + col] = f2b(v * scale);
        } else {
          v = v > 0.f ? v : 0.f;
          float mfv = b2f((Mul + (long)z * sMul)[(long)row * ldmul + col]);
          ((u16*)Cb + (long)z * sC)[(long)row * ldc + col] = f2b(v * mfv);
        }
      }
    }
  }
}

// ==========================================================================
// gemmw: 128x256 (unchanged verified structure). EPI 0=f32 | 4=bf16 raw
// CCLAMP: K clamped to m0+128 (causal attn.V)
// ==========================================================================
template<int EPI, bool CCLAMP>
__global__ __launch_bounds__(256, 2)
void gemmw(const u16* __restrict__ Ab, long sA,
           const u16* __restrict__ Bb, long sB,
           void* __restrict__ Cb, long sC,
           int grid_m, int grid_mn,
           int K, int lda, int ldb, int ldc){
  constexpr unsigned BUFB = 24576u;
  __shared__ __align__(16) u16 S[3 * 12288];

  const int nwg = gridDim.x, orig = blockIdx.x;
  const int q = nwg >> 3, r = nwg & 7, xcd = orig & 7;
  const int wgid = (xcd < r ? xcd*(q+1) : r*(q+1) + (xcd - r)*q) + (orig >> 3);
  const int z   = wgid / grid_mn;
  const int rem = wgid - z*grid_mn;
  const int nb  = rem / grid_m;
  const int mb  = rem - nb*grid_m;
  const int m0 = mb*128, n0 = nb*256;
  const int tid = threadIdx.x, lane = tid & 63, wid = tid >> 6;

  const u16* A = Ab + (long)z*sA;
  const u16* B = Bb + (long)z*sB;

  const int rS = tid >> 2;
  const int cS = (((tid & 3) ^ ((rS >> 1) & 3)) << 3);
  const u16* gA[2]; const u16* gB[4];
  #pragma unroll
  for (int i = 0; i < 2; i++) gA[i] = A + (long)(m0 + i*64 + rS)*lda + cS;
  #pragma unroll
  for (int i = 0; i < 4; i++) gB[i] = B + (long)(n0 + i*64 + rS)*ldb + cS;

  char* Sb = (char*)&S[0];
  auto stage = [&](int kt, unsigned bB){
    const int ko = kt << 5;
    gload16(gA[0] + ko, Sb + bB +          wid*1024u);
    gload16(gA[1] + ko, Sb + bB +  4096u + wid*1024u);
    #pragma unroll
    for (int i = 0; i < 4; i++)
      gload16(gB[i] + ko, Sb + bB + 8192u + i*4096u + wid*1024u);
  };

  const int wr = wid >> 1, wc = wid & 1;
  const int fr = lane & 15, fk = lane >> 4;
  const unsigned base = (unsigned)(unsigned long long)Sb;
  unsigned aAd[4], bAd[8];
  #pragma unroll
  for (int mi = 0; mi < 4; mi++){
    int row = wr*64 + mi*16 + fr;
    aAd[mi] = base + (unsigned)(row*64 + ((fk ^ ((row >> 1) & 3)) << 4));
  }
  #pragma unroll
  for (int ni = 0; ni < 8; ni++){
    int row = wc*128 + ni*16 + fr;
    bAd[ni] = base + 8192u + (unsigned)(row*64 + ((fk ^ ((row >> 1) & 3)) << 4));
  }

  const int Keff = CCLAMP ? (m0 + 128 < K ? m0 + 128 : K) : K;
  const int NT = Keff >> 5;
  const int s0 = (mb*13 + nb*7 + z*5) % NT;

  f32x4 acc[4][8] = {};

  int p1 = s0 + 1; if (p1 >= NT) p1 -= NT;
  stage(s0, 0);
  stage(p1, BUFB);
  asm volatile("s_waitcnt vmcnt(6)" ::: "memory");
  __builtin_amdgcn_s_barrier();
  __builtin_amdgcn_sched_barrier(0);

  unsigned rbB = 0, wbB = 2u*BUFB;
  for (int t = 0; t < NT; t++){
    int nx = (t + 2 < NT) ? t + 2 : NT - 1;
    int ph = s0 + nx; if (ph >= NT) ph -= NT;
    stage(ph, wbB);
    bf16x8 afr[4], bfr[8];
    #pragma unroll
    for (int ni = 0; ni < 8; ni++) bfr[ni] = ldsr(bAd[ni] + rbB);
    #pragma unroll
    for (int mi = 0; mi < 4; mi++) afr[mi] = ldsr(aAd[mi] + rbB);
    __builtin_amdgcn_s_barrier();
    asm volatile("s_waitcnt lgkmcnt(0)" ::: "memory");
    __builtin_amdgcn_sched_barrier(0);
    __builtin_amdgcn_s_setprio(1);
    #pragma unroll
    for (int mi = 0; mi < 4; mi++)
      #pragma unroll
      for (int ni = 0; ni < 8; ni++)
        acc[mi][ni] = __builtin_amdgcn_mfma_f32_16x16x32_bf16(afr[mi], bfr[ni], acc[mi][ni], 0, 0, 0);
    __builtin_amdgcn_s_setprio(0);
    __builtin_amdgcn_sched_barrier(0);
    asm volatile("s_waitcnt vmcnt(6)" ::: "memory");
    __builtin_amdgcn_s_barrier();
    __builtin_amdgcn_sched_barrier(0);
    unsigned tmp = rbB; rbB += BUFB; if (rbB == 3u*BUFB) rbB = 0;
    wbB = tmp;
  }
  asm volatile("s_waitcnt vmcnt(0)" ::: "memory");

  const int er = (lane >> 4) * 4, ec = lane & 15;
  #pragma unroll
  for (int mi = 0; mi < 4; mi++){
    #pragma unroll
    for (int ni = 0; ni < 8; ni++){
      #pragma unroll
      for (int j = 0; j < 4; j++){
        int row = m0 + wr*64 + mi*16 + er + j;
        int col = n0 + wc*128 + ni*16 + ec;
        float v = acc[mi][ni][j];
        if (EPI == 0){
          ((float*)Cb + (long)z * sC)[(long)row * ldc + col] = v;
        } else {
          ((u16*)Cb + (long)z * sC)[(long)row * ldc + col] = f2b(v);
        }
      }
    }
  }
}

// ---------- host ----------
extern "C" void kernel_launch(void* const* d_in, const int* in_sizes, int n_in,
                              void* d_out, int out_size, void* d_ws, size_t ws_size,
                              hipStream_t stream){
  (void)in_sizes; (void)n_in; (void)out_size; (void)ws_size;
  const int*   idx     = (const int*)  d_in[0];
  const float* embed   = (const float*)d_in[1];
  const float* encoder = (const float*)d_in[2];
  const float* encv    = (const float*)d_in[3];
  const float* decoder = (const float*)d_in[4];
  const float* lm_head = (const float*)d_in[5];
  const float* ln_w    = (const float*)d_in[6];
  const float* ln_b    = (const float*)d_in[7];
  float* out = (float*)d_out;

  char* p = (char*)d_ws;
  auto take = [&](size_t n){ char* r = p; p += (n + 255) & ~(size_t)255; return r; };
  u16*   encT  = (u16*)  take((size_t)NHH * ND * EE * 2);
  u16*   encvT = (u16*)  take((size_t)NHH * ND * EE * 2);
  u16*   decT  = (u16*)  take((size_t)EE * HNN * 2);
  u16*   lmhB  = (u16*)  take((size_t)VOC * EE * 2);
  float* xf    = (float*)take((size_t)TT * EE * 4);
  u16*   xb    = (u16*)  take((size_t)TT * EE * 2);
  u16*   xT    = (u16*)  take((size_t)EE * TT * 2);
  u16*   xs    = (u16*)  take((size_t)NHH * TT * ND * 2);
  char*  big   =         take((size_t)NHH * TT * TT * 4);
  u16*   attn  = (u16*)  take((size_t)NHH * TT * TT * 2);   // dead after attn.V
  u16*   yb    = (u16*)  take((size_t)NHH * TT * EE * 2);
  take((size_t)8 * TT * EE * 4);
  u16*   scores = (u16*)big;
  u16*   ybig   = (u16*)big;
  u16*   xy     = (u16*)big;
  u16*   part   = attn;    // SPLITK bf16 partials overlay dead attn

  dim3 blk(256, 1, 1);

  prep<<<dim3(37824, 1, 1), blk, 0, stream>>>(encoder, encv, decoder, lm_head,
                                              encT, encvT, decT, lmhB);

  embed_ln<<<dim3(TT, 1, 1), blk, 0, stream>>>(idx, embed, ln_w, ln_b, xf, xb);
  xpose<<<dim3(EE / 64, TT / 64, 1), blk, 0, stream>>>(xb, xT);

  const float scl = 0.022097086912079608f;  // 1/sqrt(2048)

  for (int L = 0; L < NLAYER; ++L){
    // x_sparse[h] = relu(x @ enc[h])  -> bf16 [H][T][N]
    g8<1><<<dim3(4*8*NHH), dim3(512), 0, stream>>>(
        xb, 0, encT, (long)ND * EE, xs, (long)TT * ND,
        4, 32, EE, EE, EE, ND, 0.f, (const u16*)0, 0, 0);
    // scores[h] = scale * xs[h] @ xs[h]^T -> BF16 [H][T][T] (masked blocks skipped)
    g8<2><<<dim3(4*4*NHH), dim3(512), 0, stream>>>(
        xs, (long)TT * ND, xs, (long)TT * ND, scores, (long)TT * TT,
        4, 16, ND, ND, ND, TT, scl, (const u16*)0, 0, 0);
    softmax_rows<<<dim3(TT, NHH, 1), blk, 0, stream>>>(scores, attn);
    // y[h] = attn[h] @ x  -> BF16 [H][T][E]  (causal K-clamp; overlays dead scores)
    gemmw<4,true><<<dim3(8*3*NHH), blk, 0, stream>>>(
        attn, (long)TT * TT, xT, 0, ybig, (long)TT * EE,
        8, 24, TT, TT, TT, EE);
    ln_rows<<<dim3(NHH * TT, 1, 1), blk, 0, stream>>>(ybig, yb, ln_w, ln_b);
    // xy[t][h*N+n] = relu(y[h] @ encv[h]) * xs[h]  -> bf16 [T][H*N]
    g8<3><<<dim3(4*8*NHH), dim3(512), 0, stream>>>(
        yb, (long)TT * EE, encvT, (long)ND * EE, xy, (long)ND,
        4, 32, EE, EE, EE, HNN, 0.f, xs, (long)TT * ND, ND);
    // y_mlp partials (bf16): split-K over 24576 (SPLITK=16 chunks of 1536)
    gemmw<4,false><<<dim3(8*3*SPLITK), blk, 0, stream>>>(
        xy, (long)(HNN / SPLITK), decT, (long)(HNN / SPLITK), part, (long)TT * EE,
        8, 24, HNN / SPLITK, HNN, HNN, EE);
    residual_ln<SPLITK><<<dim3(TT, 1, 1), blk, 0, stream>>>(part, xf, xf, xb, ln_w, ln_b);
    xpose<<<dim3(EE / 64, TT / 64, 1), blk, 0, stream>>>(xb, xT);
  }

  // logits = x @ lm_head^T -> f32 [T][V]
  g8<0><<<dim3(4*125), dim3(512), 0, stream>>>(
      xb, 0, lmhB, 0, out, 0,
      4, 500, EE, EE, EE, VOC, 0.f, (const u16*)0, 0, 0);
}